// Round 6
// baseline (211.205 us; speedup 1.0000x reference)
//
#include <hip/hip_runtime.h>
#include <stdint.h>

#define NSITE 512
#define DD    64
#define NB    64
#define NO    10
#define NSEG  16
#define SEGLEN 32
#define SLAB_BYTES 32768   // fp32 site slab stride
#define PACK_BYTES 16384   // packed bf16 Wstk image (front half of slab)

typedef short bf16x8 __attribute__((ext_vector_type(8)));
typedef float f32x16 __attribute__((ext_vector_type(16)));

// trunc-pack two f32 -> packed bf16 dword (lo=a, hi=b) in ONE v_perm_b32
__device__ __forceinline__ uint32_t pk2(float a, float b) {
    return __builtin_amdgcn_perm(__float_as_uint(b), __float_as_uint(a), 0x07060302);
}

// ---------------------------------------------------------------------------
// Pack W fp32 [s][l][r][w] -> bf16 K-stacked A-operand image, IN PLACE (front
// 16 KB of each 32 KB slab).  A[m][kap=2k+w] = left: W_w[k][m] (transpose),
// right: W_w[m][k].  Image layout: dword od = chunk*256 + H*128 + m5*4 + d,
// chunk = (m>>5)*8 + (kap>>4), H = (kap>>3)&1, m5 = m&31, d = ((kap&7)>>1);
// dword = {bf(w=0), bf(w=1)} at k = 8*(chunk&7) + 4H + d.  A-frag read in
// stage1 is then *(uint4*)(ring + chunk*1024 + lane*16): lane-contiguous,
// bank-conflict-free, and global_load_lds copies the image verbatim.
// ---------------------------------------------------------------------------
__global__ __launch_bounds__(256) void pack_kernel(float* __restrict__ wl,
                                                   float* __restrict__ wr) {
    const int g = blockIdx.x;                 // 0..1023
    const int right = (g >= NSITE) ? 1 : 0;
    const int s = right ? g - NSITE : g;
    float* base = (right ? wr : wl) + (size_t)s * (SLAB_BYTES / 4);

    __shared__ float2 st[DD * 65];            // padded [l][r] (w0,w1) pairs
    const float2* src2 = (const float2*)base;
    for (int e = threadIdx.x; e < DD * DD; e += 256)
        st[(e >> 6) * 65 + (e & 63)] = src2[e];
    __syncthreads();

    uint32_t* out = (uint32_t*)base;          // front 16 KB = 4096 dwords
    #pragma unroll
    for (int rr = 0; rr < 16; ++rr) {
        const int od = rr * 256 + threadIdx.x;        // coalesced writes
        const int chunk = od >> 8, i = chunk >> 3, sk = chunk & 7;
        const int H = (od >> 7) & 1, m5 = (od >> 2) & 31, d = od & 3;
        const int m = 32 * i + m5, k = 8 * sk + 4 * H + d;
        const float2 a = right ? st[m * 65 + k] : st[k * 65 + m];
        out[od] = pk2(a.x, a.y);              // lo = w0, hi = w1
    }
}

__device__ __forceinline__ void dma16(const void* gp, void* lp) {
    __builtin_amdgcn_global_load_lds(
        (const __attribute__((address_space(1))) uint32_t*)gp,
        (__attribute__((address_space(3))) uint32_t*)lp, 16, 0, 0);
}

// ---------------------------------------------------------------------------
// Stage 1: per (side, segment-of-32) x batch-PAIR: 64x64 segment products via
// MFMA, K=128/site (x-combine folded into the contraction).  256 blocks x 4
// waves = 1 block/CU, 1 wave/SIMD; each wave carries TWO batches' T in
// registers against shared A-frags (af loaded once per site, reused).
// Per SIMD per site: 64 MFMA x 32 cyc = 2048 cyc of matrix-pipe work hiding
// ~400 issue slots of VALU/LDS/DMA.  8-slot shared DMA ring (128 KB), prefetch
// depth 4, vmcnt(16)+s_barrier; a slot is rewritten 4 barriers after its last
// read (round-5's depth-3/4-slot ring was a 1-barrier race - fixed here).
// ---------------------------------------------------------------------------
__global__ __launch_bounds__(256, 1) void stage1_kernel(
        const float* __restrict__ x, float* __restrict__ wl, float* __restrict__ wr) {
    const int bid  = blockIdx.x;          // 0..255
    const int side = bid >> 7;
    const int rem  = bid & 127;
    const int seg  = rem >> 3;            // 0..15
    const int bq   = rem & 7;             // 0..7
    const int wave = threadIdx.x >> 6;
    const int lane = threadIdx.x & 63;
    const int pi   = bq * 4 + wave;       // batch pair 0..31 -> batches 2pi, 2pi+1
    const int m5   = lane & 31;
    const int H    = lane >> 5;

    __shared__ __align__(16) char ring[8][PACK_BYTES];   // 128 KB
    __shared__ float2 xs[4][2][SEGLEN];                  // [wave][batch][site]

    char* wbuf = (char*)(side ? wr : wl);

    {   // x in chain order: lanes 0-31 load batch 2pi, lanes 32-63 batch 2pi+1
        const int bb = lane >> 5, tt = lane & 31;
        const float2* xp = ((const float2*)x) + (size_t)(2 * pi + bb) * 1024
                         + (side ? NSITE : 0);
        const int sg = seg * SEGLEN + (side ? SEGLEN - 1 - tt : tt);
        xs[wave][bb][tt] = xp[sg];
    }

    auto siteAddr = [&](int t) -> const char* {
        const int sg = seg * SEGLEN + (side ? SEGLEN - 1 - t : t);
        return wbuf + (size_t)sg * SLAB_BYTES;
    };

    // prime ring slots 0..3 (each wave owns 4 of the 16 chunks)
    #pragma unroll
    for (int t0 = 0; t0 < 4; ++t0) {
        const char* sb = siteAddr(t0);
        #pragma unroll
        for (int c = 0; c < 4; ++c) {
            const int ch = wave * 4 + c;
            dma16(sb + ch * 1024 + lane * 16, ring[t0] + ch * 1024);
        }
    }

    // T := Identity for both batches (C/D layout: row=(q&3)+8(q>>2)+4H, col=32j+m5)
    f32x16 sP[2][2][2], sQ[2][2][2];      // [batch][i][j]
    #pragma unroll
    for (int bb = 0; bb < 2; ++bb)
        #pragma unroll
        for (int i = 0; i < 2; ++i)
            #pragma unroll
            for (int j = 0; j < 2; ++j)
                #pragma unroll
                for (int q = 0; q < 16; ++q) {
                    const int row = (q & 3) + 8 * (q >> 2) + 4 * H;
                    sP[bb][i][j][q] = (i == j && row == m5) ? 1.f : 0.f;
                }

    auto body = [&](int t, f32x16 (&tin)[2][2][2], f32x16 (&tout)[2][2][2]) {
        int t4 = t + 4; if (t4 > SEGLEN - 1) t4 = SEGLEN - 1;   // clamped dummy
        {
            const char* sb = siteAddr(t4);
            char* lb = ring[(t + 4) & 7];
            #pragma unroll
            for (int c = 0; c < 4; ++c) {
                const int ch = wave * 4 + c;
                dma16(sb + ch * 1024 + lane * 16, lb + ch * 1024);
            }
        }
        asm volatile("s_waitcnt vmcnt(16)" ::: "memory");   // own site-t DMAs done
        asm volatile("s_barrier" ::: "memory");             // all 16 chunks in

        const char* rb = ring[t & 7];
        uint4 af[2][8];
        #pragma unroll
        for (int i = 0; i < 2; ++i)
            #pragma unroll
            for (int sk = 0; sk < 8; ++sk)
                af[i][sk] = *(const uint4*)(rb + (i * 8 + sk) * 1024 + lane * 16);

        const float2 xA = xs[wave][0][t];
        const float2 xB = xs[wave][1][t];

        #pragma unroll
        for (int bb = 0; bb < 2; ++bb)
            #pragma unroll
            for (int i = 0; i < 2; ++i)
                #pragma unroll
                for (int j = 0; j < 2; ++j)
                    tout[bb][i][j] = 0;

        #pragma unroll
        for (int sk = 0; sk < 8; ++sk) {
            const int mi = sk >> 2, qb = 4 * (sk & 3);
            union { bf16x8 v; uint32_t u[4]; } bf[2][2];   // [batch][j]
            #pragma unroll
            for (int bb = 0; bb < 2; ++bb) {
                const float2 x01 = bb ? xB : xA;
                #pragma unroll
                for (int j = 0; j < 2; ++j)
                    #pragma unroll
                    for (int e = 0; e < 2; ++e) {
                        float2 vp;             // adjacent, even-aligned acc pair
                        vp.x = tin[bb][mi][j][qb + 2 * e];
                        vp.y = tin[bb][mi][j][qb + 2 * e + 1];
                        float2 d0, d1;
                        // d0 = {x0*vp.x, x1*vp.x}; d1 = {x0*vp.y, x1*vp.y}
                        asm("v_pk_mul_f32 %0, %1, %2 op_sel:[0,0] op_sel_hi:[1,0]"
                            : "=v"(d0) : "v"(x01), "v"(vp));
                        asm("v_pk_mul_f32 %0, %1, %2 op_sel:[0,1] op_sel_hi:[1,1]"
                            : "=v"(d1) : "v"(x01), "v"(vp));
                        bf[bb][j].u[2 * e]     = pk2(d0.x, d0.y);
                        bf[bb][j].u[2 * e + 1] = pk2(d1.x, d1.y);
                    }
            }
            #pragma unroll
            for (int i = 0; i < 2; ++i) {
                union { bf16x8 v; uint4 u; } a; a.u = af[i][sk];
                #pragma unroll
                for (int bb = 0; bb < 2; ++bb)
                    #pragma unroll
                    for (int j = 0; j < 2; ++j)
                        tout[bb][i][j] = __builtin_amdgcn_mfma_f32_32x32x16_bf16(
                            a.v, bf[bb][j].v, tout[bb][i][j], 0, 0, 0);
            }
        }
    };

    for (int t = 0; t < SEGLEN; t += 2) {
        body(t,     sP, sQ);
        body(t + 1, sQ, sP);
    }
    // result in sP (even site count)

    // write both P matrices (bf16, uint16 index c*64+r) into slab back-halves
    #pragma unroll
    for (int bb = 0; bb < 2; ++bb) {
        const int p = (2 * pi + bb) * NSEG + seg;        // 0..1023 per side
        char* pdst = wbuf + (size_t)(p >> 1) * SLAB_BYTES + PACK_BYTES + (p & 1) * 8192;
        #pragma unroll
        for (int i = 0; i < 2; ++i)
            #pragma unroll
            for (int j = 0; j < 2; ++j) {
                const int c = 32 * j + m5;
                #pragma unroll
                for (int Q = 0; Q < 4; ++Q) {
                    const int r0 = 32 * i + 8 * Q + 4 * H;
                    uint2 val;
                    val.x = pk2(sP[bb][i][j][4 * Q + 0], sP[bb][i][j][4 * Q + 1]);
                    val.y = pk2(sP[bb][i][j][4 * Q + 2], sP[bb][i][j][4 * Q + 3]);
                    *(uint2*)(pdst + c * 128 + r0 * 2) = val;
                }
            }
    }
    asm volatile("s_waitcnt vmcnt(0)" ::: "memory");   // drain DMA before endpgm
}

// ---------------------------------------------------------------------------
// Fused tail: per batch, fold 16 segment matrices into each boundary vector
// (left chain threads 0-127, right chain threads 128-255; 2 c-half waves per
// chain), then contract vL . core . wR -> out[b][0..9].  One kernel, 64 blocks.
// ---------------------------------------------------------------------------
__global__ __launch_bounds__(256) void tail_kernel(
        const float* __restrict__ wl, const float* __restrict__ wr,
        const float* __restrict__ core, float* __restrict__ out) {
    const int b    = blockIdx.x;          // 0..63
    const int tid  = threadIdx.x;
    const int side = tid >> 7;            // 0 = left, 1 = right
    const int half = (tid >> 6) & 1;      // c-half within the chain
    const int r    = tid & 63;

    __shared__ float vs[2][DD];
    __shared__ float part[2][2][DD];
    if (half == 0) vs[side][r] = (r == 0) ? 1.f : 0.f;
    __syncthreads();

    const char* wb = (const char*)(side ? wr : wl);
    for (int gi = 0; gi < NSEG; ++gi) {
        const int g = side ? (NSEG - 1 - gi) : gi;
        const int p = b * NSEG + g;
        const uint16_t* P = (const uint16_t*)(wb
            + (size_t)(p >> 1) * SLAB_BYTES + PACK_BYTES + (p & 1) * 8192);
        float acc = 0.f;
        #pragma unroll
        for (int cc = 0; cc < 32; ++cc) {
            const int c = half * 32 + cc;
            acc = fmaf(vs[side][c],
                       __uint_as_float(((uint32_t)P[c * 64 + r]) << 16), acc);
        }
        part[side][half][r] = acc;
        __syncthreads();
        if (half == 0) vs[side][r] = part[side][0][r] + part[side][1][r];
        __syncthreads();
    }

    // finalize: out[b,o] = sum_{l,r} vL[l] * core[o,l,r] * wR[r]
    const int og   = tid >> 6;            // wave 0..3
    const int lane = tid & 63;
    for (int o = og; o < NO; o += 4) {
        float a = 0.f;
        #pragma unroll 8
        for (int l = 0; l < DD; ++l)
            a += vs[0][l] * core[(o * DD + l) * DD + lane];
        a *= vs[1][lane];
        #pragma unroll
        for (int off = 32; off > 0; off >>= 1)
            a += __shfl_xor(a, off, 64);
        if (lane == 0) out[b * NO + o] = a;
    }
}

extern "C" void kernel_launch(void* const* d_in, const int* in_sizes, int n_in,
                              void* d_out, int out_size, void* d_ws, size_t ws_size,
                              hipStream_t stream) {
    const float* x    = (const float*)d_in[0];   // [64][1024][2]
    float*       wl   = (float*)d_in[1];         // [512][64][64][2] -> packed + P scratch
    const float* core = (const float*)d_in[2];   // [10][64][64]
    float*       wr   = (float*)d_in[3];         // [512][64][64][2] -> packed + P scratch

    pack_kernel<<<2 * NSITE, 256, 0, stream>>>(wl, wr);
    stage1_kernel<<<256, 256, 0, stream>>>(x, wl, wr);
    tail_kernel<<<NB, 256, 0, stream>>>(wl, wr, core, (float*)d_out);
}

// Round 7
// 210.435 us; speedup vs baseline: 1.0037x; 1.0037x over previous
//
#include <hip/hip_runtime.h>
#include <stdint.h>

#define NSITE 512
#define DD    64
#define NB    64
#define NO    10
#define NSEG  16
#define SEGLEN 32
#define SLAB_BYTES 32768   // fp32 site slab stride
#define PACK_BYTES 16384   // packed bf16 Wstk image (front half of slab)

typedef short bf16x8 __attribute__((ext_vector_type(8)));
typedef float f32x16 __attribute__((ext_vector_type(16)));

// trunc-pack two f32 -> packed bf16 dword (lo=a, hi=b) in ONE v_perm_b32
__device__ __forceinline__ uint32_t pk2(float a, float b) {
    return __builtin_amdgcn_perm(__float_as_uint(b), __float_as_uint(a), 0x07060302);
}

// ---------------------------------------------------------------------------
// Pack W fp32 [s][l][r][w] -> bf16 K-stacked A-operand image, IN PLACE (front
// 16 KB of each 32 KB slab).  A[m][kap=2k+w] = left: W_w[k][m] (transpose),
// right: W_w[m][k].  Image layout: dword od = chunk*256 + H*128 + m5*4 + d,
// chunk = (m>>5)*8 + (kap>>4), H = (kap>>3)&1, m5 = m&31, d = ((kap&7)>>1);
// dword = {bf(w=0), bf(w=1)} at k = 8*(chunk&7) + 4H + d.  A-frag read in
// stage1 is then *(uint4*)(buf + chunk*1024 + lane*16): lane-contiguous,
// bank-conflict-free, and global_load_lds copies the image verbatim.
// ---------------------------------------------------------------------------
__global__ __launch_bounds__(256) void pack_kernel(float* __restrict__ wl,
                                                   float* __restrict__ wr) {
    const int g = blockIdx.x;                 // 0..1023
    const int right = (g >= NSITE) ? 1 : 0;
    const int s = right ? g - NSITE : g;
    float* base = (right ? wr : wl) + (size_t)s * (SLAB_BYTES / 4);

    __shared__ float2 st[DD * 65];            // padded [l][r] (w0,w1) pairs
    const float2* src2 = (const float2*)base;
    for (int e = threadIdx.x; e < DD * DD; e += 256)
        st[(e >> 6) * 65 + (e & 63)] = src2[e];
    __syncthreads();

    uint32_t* out = (uint32_t*)base;          // front 16 KB = 4096 dwords
    #pragma unroll
    for (int rr = 0; rr < 16; ++rr) {
        const int od = rr * 256 + threadIdx.x;        // coalesced writes
        const int chunk = od >> 8, i = chunk >> 3, sk = chunk & 7;
        const int H = (od >> 7) & 1, m5 = (od >> 2) & 31, d = od & 3;
        const int m = 32 * i + m5, k = 8 * sk + 4 * H + d;
        const float2 a = right ? st[m * 65 + k] : st[k * 65 + m];
        out[od] = pk2(a.x, a.y);              // lo = w0, hi = w1
    }
}

__device__ __forceinline__ void dma16(const void* gp, void* lp) {
    __builtin_amdgcn_global_load_lds(
        (const __attribute__((address_space(1))) uint32_t*)gp,
        (__attribute__((address_space(3))) uint32_t*)lp, 16, 0, 0);
}

// ---------------------------------------------------------------------------
// Stage 1: one wave per (side, segment, batch) product; 512 blocks x 4 waves,
// 2 blocks/CU -> 2 waves/SIMD.  NO BARRIERS: each wave owns a private 16 KB
// slab buffer, DMAs the whole site slab itself (16 x 1 KB global_load_lds),
// and syncs only its own DMAs with per-wave s_waitcnt vmcnt(0).  Waves
// free-run, so one wave's VALU/LDS/DMA phase overlaps the other's MFMA phase
// (rounds 4-6 were phase-locked by the shared-ring s_barrier).
// Per site: wait own DMAs -> 16 ds_read_b128 (af) -> B-prep VALU (from acc)
// -> lgkmcnt(0) -> issue next site's DMAs (fly under the MFMAs) -> 32 MFMA.
// Zero-C trick: first MFMA of each accumulator uses a persistent zero f32x16
// as C, eliminating 128 per-site zero-init movs.
// ---------------------------------------------------------------------------
__global__ __launch_bounds__(256, 2) void stage1_kernel(
        const float* __restrict__ x, float* __restrict__ wl, float* __restrict__ wr) {
    const int wave = threadIdx.x >> 6;
    const int lane = threadIdx.x & 63;
    const int p    = blockIdx.x * 4 + wave;   // 0..2047
    const int side = p >> 10;
    const int seg  = (p >> 6) & 15;
    const int b    = p & 63;
    const int m5   = lane & 31;
    const int H    = lane >> 5;

    __shared__ __align__(16) char bufs[4][PACK_BYTES];   // 64 KB: private per wave
    __shared__ float2 xs[4][SEGLEN];

    char* wbuf = (char*)(side ? wr : wl);
    char* buf  = bufs[wave];

    if (lane < SEGLEN) {   // x in chain order (written+read by the same wave: no barrier)
        const float2* xp = ((const float2*)x) + (size_t)b * 1024 + (side ? NSITE : 0);
        const int sg = seg * SEGLEN + (side ? SEGLEN - 1 - lane : lane);
        xs[wave][lane] = xp[sg];
    }

    auto siteAddr = [&](int t) -> const char* {
        const int sg = seg * SEGLEN + (side ? SEGLEN - 1 - t : t);
        return wbuf + (size_t)sg * SLAB_BYTES;
    };

    {   // prime site 0 (whole slab, this wave)
        const char* sb = siteAddr(0);
        #pragma unroll
        for (int c = 0; c < 16; ++c)
            dma16(sb + c * 1024 + lane * 16, buf + c * 1024);
    }

    // persistent zero accumulator (C for each site's first MFMA)
    f32x16 zc;
    #pragma unroll
    for (int q = 0; q < 16; ++q) zc[q] = 0.f;

    // T := Identity (C/D layout: row=(q&3)+8(q>>2)+4H, col=32j+m5), once
    f32x16 sP[2][2], sQ[2][2];
    #pragma unroll
    for (int i = 0; i < 2; ++i)
        #pragma unroll
        for (int j = 0; j < 2; ++j)
            #pragma unroll
            for (int q = 0; q < 16; ++q) {
                const int row = (q & 3) + 8 * (q >> 2) + 4 * H;
                sP[i][j][q] = (i == j && row == m5) ? 1.f : 0.f;
            }

    auto body = [&](int t, f32x16 (&tin)[2][2], f32x16 (&tout)[2][2]) {
        asm volatile("s_waitcnt vmcnt(0)" ::: "memory");   // own site-t slab landed

        // A-frags for this site (16 x ds_read_b128, conflict-free)
        uint4 af[2][8];
        #pragma unroll
        for (int i = 0; i < 2; ++i)
            #pragma unroll
            for (int sk = 0; sk < 8; ++sk)
                af[i][sk] = *(const uint4*)(buf + (i * 8 + sk) * 1024 + lane * 16);

        const float2 xv = xs[wave][t];
        float2 x01; x01.x = xv.x; x01.y = xv.y;

        // B-prep from tin (registers only; overlaps the af-read latency)
        union { bf16x8 v; uint32_t u[4]; } bf[8][2];   // [sk][j]
        #pragma unroll
        for (int sk = 0; sk < 8; ++sk) {
            const int mi = sk >> 2, qb = 4 * (sk & 3);
            #pragma unroll
            for (int j = 0; j < 2; ++j)
                #pragma unroll
                for (int e = 0; e < 2; ++e) {
                    float2 vp;                 // adjacent, even-aligned acc pair
                    vp.x = tin[mi][j][qb + 2 * e];
                    vp.y = tin[mi][j][qb + 2 * e + 1];
                    float2 d0, d1;
                    // d0 = {x0*vp.x, x1*vp.x}; d1 = {x0*vp.y, x1*vp.y}
                    asm("v_pk_mul_f32 %0, %1, %2 op_sel:[0,0] op_sel_hi:[1,0]"
                        : "=v"(d0) : "v"(x01), "v"(vp));
                    asm("v_pk_mul_f32 %0, %1, %2 op_sel:[0,1] op_sel_hi:[1,1]"
                        : "=v"(d1) : "v"(x01), "v"(vp));
                    bf[sk][j].u[2 * e]     = pk2(d0.x, d0.y);
                    bf[sk][j].u[2 * e + 1] = pk2(d1.x, d1.y);
                }
        }

        // all LDS reads (af, xs) complete -> safe to overwrite buf via DMA
        asm volatile("s_waitcnt lgkmcnt(0)" ::: "memory");
        if (t + 1 < SEGLEN) {                  // prefetch next site under the MFMAs
            const char* sb = siteAddr(t + 1);
            #pragma unroll
            for (int c = 0; c < 16; ++c)
                dma16(sb + c * 1024 + lane * 16, buf + c * 1024);
        }

        // 32 MFMAs; sk=0 takes C=zc (no per-site accumulator zero-init)
        #pragma unroll
        for (int sk = 0; sk < 8; ++sk)
            #pragma unroll
            for (int i = 0; i < 2; ++i) {
                union { bf16x8 v; uint4 u; } a; a.u = af[i][sk];
                #pragma unroll
                for (int j = 0; j < 2; ++j)
                    tout[i][j] = __builtin_amdgcn_mfma_f32_32x32x16_bf16(
                        a.v, bf[sk][j].v, sk == 0 ? zc : tout[i][j], 0, 0, 0);
            }
    };

    for (int t = 0; t < SEGLEN; t += 2) {
        body(t,     sP, sQ);
        body(t + 1, sQ, sP);
    }
    // result in sP (even site count)

    // write P (final T, bf16, uint16 index c*64+r) into slab back-halves
    {
        const int pp = b * NSEG + seg;                   // 0..1023 per side
        char* pdst = wbuf + (size_t)(pp >> 1) * SLAB_BYTES + PACK_BYTES + (pp & 1) * 8192;
        #pragma unroll
        for (int i = 0; i < 2; ++i)
            #pragma unroll
            for (int j = 0; j < 2; ++j) {
                const int c = 32 * j + m5;
                #pragma unroll
                for (int Q = 0; Q < 4; ++Q) {
                    const int r0 = 32 * i + 8 * Q + 4 * H;
                    uint2 val;
                    val.x = pk2(sP[i][j][4 * Q + 0], sP[i][j][4 * Q + 1]);
                    val.y = pk2(sP[i][j][4 * Q + 2], sP[i][j][4 * Q + 3]);
                    *(uint2*)(pdst + c * 128 + r0 * 2) = val;
                }
            }
    }
    asm volatile("s_waitcnt vmcnt(0)" ::: "memory");   // drain before endpgm
}

// ---------------------------------------------------------------------------
// Fused tail: per batch, fold 16 segment matrices into each boundary vector
// (left chain threads 0-127, right chain threads 128-255; 2 c-half waves per
// chain), then contract vL . core . wR -> out[b][0..9].  One kernel, 64 blocks.
// ---------------------------------------------------------------------------
__global__ __launch_bounds__(256) void tail_kernel(
        const float* __restrict__ wl, const float* __restrict__ wr,
        const float* __restrict__ core, float* __restrict__ out) {
    const int b    = blockIdx.x;          // 0..63
    const int tid  = threadIdx.x;
    const int side = tid >> 7;            // 0 = left, 1 = right
    const int half = (tid >> 6) & 1;      // c-half within the chain
    const int r    = tid & 63;

    __shared__ float vs[2][DD];
    __shared__ float part[2][2][DD];
    if (half == 0) vs[side][r] = (r == 0) ? 1.f : 0.f;
    __syncthreads();

    const char* wb = (const char*)(side ? wr : wl);
    for (int gi = 0; gi < NSEG; ++gi) {
        const int g = side ? (NSEG - 1 - gi) : gi;
        const int p = b * NSEG + g;
        const uint16_t* P = (const uint16_t*)(wb
            + (size_t)(p >> 1) * SLAB_BYTES + PACK_BYTES + (p & 1) * 8192);
        float acc = 0.f;
        #pragma unroll
        for (int cc = 0; cc < 32; ++cc) {
            const int c = half * 32 + cc;
            acc = fmaf(vs[side][c],
                       __uint_as_float(((uint32_t)P[c * 64 + r]) << 16), acc);
        }
        part[side][half][r] = acc;
        __syncthreads();
        if (half == 0) vs[side][r] = part[side][0][r] + part[side][1][r];
        __syncthreads();
    }

    // finalize: out[b,o] = sum_{l,r} vL[l] * core[o,l,r] * wR[r]
    const int og   = tid >> 6;            // wave 0..3
    const int lane = tid & 63;
    for (int o = og; o < NO; o += 4) {
        float a = 0.f;
        #pragma unroll 8
        for (int l = 0; l < DD; ++l)
            a += vs[0][l] * core[(o * DD + l) * DD + lane];
        a *= vs[1][lane];
        #pragma unroll
        for (int off = 32; off > 0; off >>= 1)
            a += __shfl_xor(a, off, 64);
        if (lane == 0) out[b * NO + o] = a;
    }
}

extern "C" void kernel_launch(void* const* d_in, const int* in_sizes, int n_in,
                              void* d_out, int out_size, void* d_ws, size_t ws_size,
                              hipStream_t stream) {
    const float* x    = (const float*)d_in[0];   // [64][1024][2]
    float*       wl   = (float*)d_in[1];         // [512][64][64][2] -> packed + P scratch
    const float* core = (const float*)d_in[2];   // [10][64][64]
    float*       wr   = (float*)d_in[3];         // [512][64][64][2] -> packed + P scratch

    pack_kernel<<<2 * NSITE, 256, 0, stream>>>(wl, wr);
    stage1_kernel<<<512, 256, 0, stream>>>(x, wl, wr);
    tail_kernel<<<NB, 256, 0, stream>>>(wl, wr, core, (float*)d_out);
}

// Round 8
// 193.881 us; speedup vs baseline: 1.0894x; 1.0854x over previous
//
#include <hip/hip_runtime.h>
#include <stdint.h>

#define NSITE 512
#define DD    64
#define NB    64
#define NO    10
#define NSEG  16
#define SEGLEN 32
#define SLAB_BYTES 32768   // fp32 site slab stride
#define PACK_BYTES 16384   // packed bf16 Wstk image (front half of slab)

typedef short bf16x8 __attribute__((ext_vector_type(8)));
typedef float f32x16 __attribute__((ext_vector_type(16)));

// trunc-pack two f32 -> packed bf16 dword (lo=a, hi=b) in ONE v_perm_b32
__device__ __forceinline__ uint32_t pk2(float a, float b) {
    return __builtin_amdgcn_perm(__float_as_uint(b), __float_as_uint(a), 0x07060302);
}

// ---------------------------------------------------------------------------
// Pack W fp32 [s][l][r][w] -> bf16 K-stacked A-operand image, IN PLACE (front
// 16 KB of each 32 KB slab).  A[m][kap=2k+w] = left: W_w[k][m] (transpose),
// right: W_w[m][k].  Image layout: dword od = chunk*256 + H*128 + m5*4 + d,
// chunk = (m>>5)*8 + (kap>>4), H = (kap>>3)&1, m5 = m&31, d = ((kap&7)>>1);
// dword = {bf(w=0), bf(w=1)} at k = 8*(chunk&7) + 4H + d.  A-frag read in
// stage1 is then *(uint4*)(buf + chunk*1024 + lane*16): lane-contiguous,
// bank-conflict-free, and global_load_lds copies the image verbatim.
// ---------------------------------------------------------------------------
__global__ __launch_bounds__(256) void pack_kernel(float* __restrict__ wl,
                                                   float* __restrict__ wr) {
    const int g = blockIdx.x;                 // 0..1023
    const int right = (g >= NSITE) ? 1 : 0;
    const int s = right ? g - NSITE : g;
    float* base = (right ? wr : wl) + (size_t)s * (SLAB_BYTES / 4);

    __shared__ float2 st[DD * 65];            // padded [l][r] (w0,w1) pairs
    const float2* src2 = (const float2*)base;
    for (int e = threadIdx.x; e < DD * DD; e += 256)
        st[(e >> 6) * 65 + (e & 63)] = src2[e];
    __syncthreads();

    uint32_t* out = (uint32_t*)base;          // front 16 KB = 4096 dwords
    #pragma unroll
    for (int rr = 0; rr < 16; ++rr) {
        const int od = rr * 256 + threadIdx.x;        // coalesced writes
        const int chunk = od >> 8, i = chunk >> 3, sk = chunk & 7;
        const int H = (od >> 7) & 1, m5 = (od >> 2) & 31, d = od & 3;
        const int m = 32 * i + m5, k = 8 * sk + 4 * H + d;
        const float2 a = right ? st[m * 65 + k] : st[k * 65 + m];
        out[od] = pk2(a.x, a.y);              // lo = w0, hi = w1
    }
}

__device__ __forceinline__ void dma16(const void* gp, void* lp) {
    __builtin_amdgcn_global_load_lds(
        (const __attribute__((address_space(1))) uint32_t*)gp,
        (__attribute__((address_space(3))) uint32_t*)lp, 16, 0, 0);
}

// ---------------------------------------------------------------------------
// Stage 1: 512-thread blocks (8 waves) x 512 blocks = 2 blocks/CU ->
// 4 waves/SIMD.  A block owns (side, seg, 4 batches); wave w handles product
// prod = w>>1 (one batch) x column-half jh = w&1 (j-SPLIT keeps per-wave state
// ~112 VGPR <= the 128 needed for 4 waves/SIMD).  All 8 waves SHARE one
// 4-slot slab ring (DMA-LDS-write traffic /8 vs round 7's private buffers,
// which saturated the LDS port: reads+writes 256 KB/CU/site).  Cadence:
// prefetch depth 2, each wave DMAs 2 chunks/site, s_waitcnt vmcnt(4) +
// s_barrier; a slot is rewritten 2 barriers after its readers finished
// (round-4-proven).  Cross-block phase offsets on each SIMD (2 waves from
// each of 2 independent blocks) fill one block's MFMA phase with the other's
// VALU/LDS phase - the staggering rounds 4-7 lacked.
// ---------------------------------------------------------------------------
__global__ __launch_bounds__(512, 4) void stage1_kernel(
        const float* __restrict__ x, float* __restrict__ wl, float* __restrict__ wr) {
    const int bid  = blockIdx.x;          // 0..511
    const int side = bid >> 8;
    const int seg  = (bid >> 4) & 15;
    const int bg   = bid & 15;            // batch group (4 batches)
    const int wave = threadIdx.x >> 6;    // 0..7
    const int lane = threadIdx.x & 63;
    const int prod = wave >> 1;           // 0..3 within block
    const int jh   = wave & 1;            // column half
    const int b    = bg * 4 + prod;
    const int m5   = lane & 31;
    const int H    = lane >> 5;

    __shared__ __align__(16) char ring[4][PACK_BYTES];   // 64 KB shared slab ring
    __shared__ float2 xs[4][SEGLEN];

    char* wbuf = (char*)(side ? wr : wl);

    if (jh == 0 && lane < SEGLEN) {       // x in chain order, one loader per product
        const float2* xp = ((const float2*)x) + (size_t)b * 1024 + (side ? NSITE : 0);
        const int sg = seg * SEGLEN + (side ? SEGLEN - 1 - lane : lane);
        xs[prod][lane] = xp[sg];
    }

    auto siteAddr = [&](int t) -> const char* {
        const int sg = seg * SEGLEN + (side ? SEGLEN - 1 - t : t);
        return wbuf + (size_t)sg * SLAB_BYTES;
    };

    // prime ring slots 0,1 (each wave owns 2 of the 16 chunks)
    #pragma unroll
    for (int t0 = 0; t0 < 2; ++t0) {
        const char* sb = siteAddr(t0);
        #pragma unroll
        for (int c = 0; c < 2; ++c) {
            const int ch = wave * 2 + c;
            dma16(sb + ch * 1024 + lane * 16, ring[t0] + ch * 1024);
        }
    }

    // persistent zero C (avoids per-site acc zero-init AND acc ping-pong)
    f32x16 zc;
    #pragma unroll
    for (int q = 0; q < 16; ++q) zc[q] = 0.f;

    // acc[i] = rows 32i..32i+31 x cols 32jh..32jh+31 of T; T := Identity.
    // C/D: row-in-tile rr=(q&3)+8(q>>2)+4H, col-in-tile m5 -> 1 iff i==jh && rr==m5.
    f32x16 acc[2];
    #pragma unroll
    for (int i = 0; i < 2; ++i)
        #pragma unroll
        for (int q = 0; q < 16; ++q) {
            const int rr = (q & 3) + 8 * (q >> 2) + 4 * H;
            acc[i][q] = (i == jh && rr == m5) ? 1.f : 0.f;
        }

    for (int t = 0; t < SEGLEN; ++t) {
        int t2 = t + 2; if (t2 > SEGLEN - 1) t2 = SEGLEN - 1;   // clamped dummy
        {
            const char* sb = siteAddr(t2);
            char* lb = ring[(t + 2) & 3];
            #pragma unroll
            for (int c = 0; c < 2; ++c) {
                const int ch = wave * 2 + c;
                dma16(sb + ch * 1024 + lane * 16, lb + ch * 1024);
            }
        }
        asm volatile("s_waitcnt vmcnt(4)" ::: "memory");   // own site-t DMAs done
        asm volatile("s_barrier" ::: "memory");            // all 16 chunks in

        const char* rb = ring[t & 3];
        const float2 xv = xs[prod][t];
        float2 x01; x01.x = xv.x; x01.y = xv.y;

        // B-prep: all 8 kap-blocks for my column half, from acc (registers only).
        // bf[sk] covers kap = 16sk+8H+{0..7}; source row k = 8sk+4H+dlt lives in
        // acc[sk>>2] regs 4(sk&3)+dlt (verified mapping, rounds 4-7).
        union { bf16x8 v; uint32_t u[4]; } bf[8];
        #pragma unroll
        for (int sk = 0; sk < 8; ++sk) {
            const int mi = sk >> 2, qb = 4 * (sk & 3);
            #pragma unroll
            for (int e = 0; e < 2; ++e) {
                float2 vp;                    // adjacent, even-aligned acc pair
                vp.x = acc[mi][qb + 2 * e];
                vp.y = acc[mi][qb + 2 * e + 1];
                float2 d0, d1;
                // d0 = {x0*vp.x, x1*vp.x}; d1 = {x0*vp.y, x1*vp.y}
                asm("v_pk_mul_f32 %0, %1, %2 op_sel:[0,0] op_sel_hi:[1,0]"
                    : "=v"(d0) : "v"(x01), "v"(vp));
                asm("v_pk_mul_f32 %0, %1, %2 op_sel:[0,1] op_sel_hi:[1,1]"
                    : "=v"(d1) : "v"(x01), "v"(vp));
                bf[sk].u[2 * e]     = pk2(d0.x, d0.y);
                bf[sk].u[2 * e + 1] = pk2(d1.x, d1.y);
            }
        }

        // 16 MFMAs, af streamed from the shared ring (2 chains i=0,1 interleave);
        // in-place C=D is safe: all bf captured acc before the first overwrite.
        #pragma unroll
        for (int sk = 0; sk < 8; ++sk)
            #pragma unroll
            for (int i = 0; i < 2; ++i) {
                union { bf16x8 v; uint4 u; } a;
                a.u = *(const uint4*)(rb + (i * 8 + sk) * 1024 + lane * 16);
                acc[i] = __builtin_amdgcn_mfma_f32_32x32x16_bf16(
                    a.v, bf[sk].v, sk == 0 ? zc : acc[i], 0, 0, 0);
            }
    }

    // write my column-half of P (bf16, uint16 index c*64 + r) to slab back-half
    {
        const int pp = b * NSEG + seg;                   // 0..1023 per side
        char* pdst = wbuf + (size_t)(pp >> 1) * SLAB_BYTES + PACK_BYTES + (pp & 1) * 8192;
        const int c = 32 * jh + m5;
        #pragma unroll
        for (int i = 0; i < 2; ++i)
            #pragma unroll
            for (int Q = 0; Q < 4; ++Q) {
                const int r0 = 32 * i + 8 * Q + 4 * H;
                uint2 val;
                val.x = pk2(acc[i][4 * Q + 0], acc[i][4 * Q + 1]);
                val.y = pk2(acc[i][4 * Q + 2], acc[i][4 * Q + 3]);
                *(uint2*)(pdst + c * 128 + r0 * 2) = val;
            }
    }
    asm volatile("s_waitcnt vmcnt(0)" ::: "memory");   // drain DMA before endpgm
}

// ---------------------------------------------------------------------------
// Fused tail: per batch, fold 16 segment matrices into each boundary vector
// (left chain threads 0-127, right chain threads 128-255; 2 c-half waves per
// chain), then contract vL . core . wR -> out[b][0..9].  One kernel, 64 blocks.
// ---------------------------------------------------------------------------
__global__ __launch_bounds__(256) void tail_kernel(
        const float* __restrict__ wl, const float* __restrict__ wr,
        const float* __restrict__ core, float* __restrict__ out) {
    const int b    = blockIdx.x;          // 0..63
    const int tid  = threadIdx.x;
    const int side = tid >> 7;            // 0 = left, 1 = right
    const int half = (tid >> 6) & 1;      // c-half within the chain
    const int r    = tid & 63;

    __shared__ float vs[2][DD];
    __shared__ float part[2][2][DD];
    if (half == 0) vs[side][r] = (r == 0) ? 1.f : 0.f;
    __syncthreads();

    const char* wb = (const char*)(side ? wr : wl);
    for (int gi = 0; gi < NSEG; ++gi) {
        const int g = side ? (NSEG - 1 - gi) : gi;
        const int p = b * NSEG + g;
        const uint16_t* P = (const uint16_t*)(wb
            + (size_t)(p >> 1) * SLAB_BYTES + PACK_BYTES + (p & 1) * 8192);
        float acc = 0.f;
        #pragma unroll
        for (int cc = 0; cc < 32; ++cc) {
            const int c = half * 32 + cc;
            acc = fmaf(vs[side][c],
                       __uint_as_float(((uint32_t)P[c * 64 + r]) << 16), acc);
        }
        part[side][half][r] = acc;
        __syncthreads();
        if (half == 0) vs[side][r] = part[side][0][r] + part[side][1][r];
        __syncthreads();
    }

    // finalize: out[b,o] = sum_{l,r} vL[l] * core[o,l,r] * wR[r]
    const int og   = tid >> 6;            // wave 0..3
    const int lane = tid & 63;
    for (int o = og; o < NO; o += 4) {
        float a = 0.f;
        #pragma unroll 8
        for (int l = 0; l < DD; ++l)
            a += vs[0][l] * core[(o * DD + l) * DD + lane];
        a *= vs[1][lane];
        #pragma unroll
        for (int off = 32; off > 0; off >>= 1)
            a += __shfl_xor(a, off, 64);
        if (lane == 0) out[b * NO + o] = a;
    }
}

extern "C" void kernel_launch(void* const* d_in, const int* in_sizes, int n_in,
                              void* d_out, int out_size, void* d_ws, size_t ws_size,
                              hipStream_t stream) {
    const float* x    = (const float*)d_in[0];   // [64][1024][2]
    float*       wl   = (float*)d_in[1];         // [512][64][64][2] -> packed + P scratch
    const float* core = (const float*)d_in[2];   // [10][64][64]
    float*       wr   = (float*)d_in[3];         // [512][64][64][2] -> packed + P scratch

    pack_kernel<<<2 * NSITE, 256, 0, stream>>>(wl, wr);
    stage1_kernel<<<512, 512, 0, stream>>>(x, wl, wr);
    tail_kernel<<<NB, 256, 0, stream>>>(wl, wr, core, (float*)d_out);
}